// Round 7
// baseline (599.154 us; speedup 1.0000x reference)
//
#include <hip/hip_runtime.h>

#define N_NODES 8192
#define IN_F    256
#define OUT_F   128
#define ALPHA_S 0.2f

typedef __attribute__((ext_vector_type(8))) short  short8;
typedef __attribute__((ext_vector_type(4))) short  short4v;
typedef __attribute__((ext_vector_type(4))) float  floatx4;
typedef __attribute__((ext_vector_type(4))) int    intx4;
typedef __attribute__((ext_vector_type(4))) float  fx4;

static __device__ __forceinline__ short f2bf(float f) {
    union { float f; unsigned int i; } u; u.f = f;
    unsigned int r = u.i + 0x7FFFu + ((u.i >> 16) & 1u);  // RNE
    return (short)(r >> 16);
}

// ---------------------------------------------------------------------------
// k_zero: zero numerator (d_out, 1048576 floats) + denominator (ws, 8192 floats)
// ---------------------------------------------------------------------------
__global__ void k_zero(float4* __restrict__ out4, float4* __restrict__ den4) {
    const int i = blockIdx.x * 256 + threadIdx.x;   // grid 1032 -> 264192 exact
    float4 z; z.x = 0.f; z.y = 0.f; z.z = 0.f; z.w = 0.f;
    if (i < 262144) out4[i] = z;
    else if (i < 264192) den4[i - 262144] = z;
}

// ---------------------------------------------------------------------------
// k_wh: Wh = h @ W via bf16 MFMA -> WhT bf16 [OUT_F][N_NODES].
//       src/dst fp32-exact via q1=W@a1, q2=W@a2 folded into W staging.
// 256 blocks x 512 threads, 32 rows/block. (R5-validated; unchanged)
// ---------------------------------------------------------------------------
__global__ __launch_bounds__(512) void k_wh(
    const float* __restrict__ h,    // [N][IN_F] fp32
    const float* __restrict__ W,    // [IN_F][OUT_F] fp32
    const float* __restrict__ a,    // [2*OUT_F] fp32
    short* __restrict__ WhT,        // [OUT_F][N] bf16
    float* __restrict__ src,
    float* __restrict__ dst)
{
    __shared__ short Wt[OUT_F][IN_F + 8];
    __shared__ short htile[32][IN_F + 8];
    __shared__ float q1s[IN_F], q2s[IN_F];
    __shared__ short wh_t[OUT_F][40];

    const int t      = threadIdx.x;
    const int lane   = t & 63;
    const int wave   = t >> 6;
    const int r_base = blockIdx.x * 32;

#pragma unroll
    for (int rep = 0; rep < 4; ++rep) {
        const int idx = rep * 8192 + t * 16;
        const int k   = idx >> 7;
        const int f   = idx & 127;
        fx4 w0 = *(const fx4*)(W + idx);
        fx4 w1 = *(const fx4*)(W + idx + 4);
        fx4 w2 = *(const fx4*)(W + idx + 8);
        fx4 w3 = *(const fx4*)(W + idx + 12);
        fx4 a10 = *(const fx4*)(a + f);
        fx4 a11 = *(const fx4*)(a + f + 4);
        fx4 a12 = *(const fx4*)(a + f + 8);
        fx4 a13 = *(const fx4*)(a + f + 12);
        fx4 a20 = *(const fx4*)(a + OUT_F + f);
        fx4 a21 = *(const fx4*)(a + OUT_F + f + 4);
        fx4 a22 = *(const fx4*)(a + OUT_F + f + 8);
        fx4 a23 = *(const fx4*)(a + OUT_F + f + 12);
        float p1 = 0.f, p2 = 0.f;
#pragma unroll
        for (int e = 0; e < 4; ++e) {
            p1 = fmaf(w0[e], a10[e], p1); p2 = fmaf(w0[e], a20[e], p2);
            p1 = fmaf(w1[e], a11[e], p1); p2 = fmaf(w1[e], a21[e], p2);
            p1 = fmaf(w2[e], a12[e], p1); p2 = fmaf(w2[e], a22[e], p2);
            p1 = fmaf(w3[e], a13[e], p1); p2 = fmaf(w3[e], a23[e], p2);
        }
#pragma unroll
        for (int e = 0; e < 4; ++e) {
            Wt[f + e][k]      = f2bf(w0[e]);
            Wt[f + 4 + e][k]  = f2bf(w1[e]);
            Wt[f + 8 + e][k]  = f2bf(w2[e]);
            Wt[f + 12 + e][k] = f2bf(w3[e]);
        }
#pragma unroll
        for (int m = 1; m < 8; m <<= 1) {
            p1 += __shfl_xor(p1, m, 64);
            p2 += __shfl_xor(p2, m, 64);
        }
        if ((t & 7) == 0) { q1s[k] = p1; q2s[k] = p2; }
    }

    const int r0   = t >> 4;
    const int fgrp = t & 15;
    const int k0   = fgrp * 16;
    fx4 h0, h1, h2, h3;
    {
        const float* hp = h + (size_t)(r_base + r0) * IN_F + k0;
        h0 = *(const fx4*)hp; h1 = *(const fx4*)(hp + 4);
        h2 = *(const fx4*)(hp + 8); h3 = *(const fx4*)(hp + 12);
        short8 b0, b1;
#pragma unroll
        for (int e = 0; e < 4; ++e) {
            b0[e]     = f2bf(h0[e]); b0[4 + e] = f2bf(h1[e]);
            b1[e]     = f2bf(h2[e]); b1[4 + e] = f2bf(h3[e]);
        }
        *(short8*)&htile[r0][k0]     = b0;
        *(short8*)&htile[r0][k0 + 8] = b1;
    }
    __syncthreads();

    {
        float sp = 0.f, dp = 0.f;
#pragma unroll
        for (int e = 0; e < 4; ++e) {
            sp = fmaf(h0[e], q1s[k0 + e], sp);      dp = fmaf(h0[e], q2s[k0 + e], dp);
            sp = fmaf(h1[e], q1s[k0 + 4 + e], sp);  dp = fmaf(h1[e], q2s[k0 + 4 + e], dp);
            sp = fmaf(h2[e], q1s[k0 + 8 + e], sp);  dp = fmaf(h2[e], q2s[k0 + 8 + e], dp);
            sp = fmaf(h3[e], q1s[k0 + 12 + e], sp); dp = fmaf(h3[e], q2s[k0 + 12 + e], dp);
        }
#pragma unroll
        for (int m = 1; m < 16; m <<= 1) {
            sp += __shfl_xor(sp, m, 64);
            dp += __shfl_xor(dp, m, 64);
        }
        if (fgrp == 0) { src[r_base + r0] = sp; dst[r_base + r0] = dp; }
    }

    const int ln15 = lane & 15;
    const int q    = lane >> 4;
    const int f0   = wave * 16;
    floatx4 c0 = {0.f, 0.f, 0.f, 0.f};
    floatx4 c1 = {0.f, 0.f, 0.f, 0.f};
#pragma unroll
    for (int s = 0; s < 8; ++s) {
        short8 bf  = *(const short8*)&Wt[f0 + ln15][s * 32 + q * 8];
        short8 a0f = *(const short8*)&htile[ln15][s * 32 + q * 8];
        short8 a1f = *(const short8*)&htile[16 + ln15][s * 32 + q * 8];
        c0 = __builtin_amdgcn_mfma_f32_16x16x32_bf16(a0f, bf, c0, 0, 0, 0);
        c1 = __builtin_amdgcn_mfma_f32_16x16x32_bf16(a1f, bf, c1, 0, 0, 0);
    }
    {
        short4v p0, p1;
#pragma unroll
        for (int r = 0; r < 4; ++r) { p0[r] = f2bf(c0[r]); p1[r] = f2bf(c1[r]); }
        *(short4v*)&wh_t[f0 + ln15][q * 4]      = p0;
        *(short4v*)&wh_t[f0 + ln15][16 + q * 4] = p1;
    }
    __syncthreads();
    {
        const int f    = t >> 2;
        const int half = t & 3;
        *(short8*)(WhT + (size_t)f * N_NODES + r_base + half * 8) =
            *(const short8*)&wh_t[f][half * 8];
    }
}

// ---------------------------------------------------------------------------
// k_attn: direct extension of the R5-VALIDATED structure, BM 32 -> 64.
// grid 512 (= 128 row-groups x 4 j-chunks) x 512 threads, LDS 2 x 17.4 KB.
// Register-prefetched staging; one barrier/iter; atomic fp32 partials.
// Staging: 8 threads/row x 16 j. Compute: 4 row-tiles/wave, wave 0 does denom.
// ---------------------------------------------------------------------------
#define BM2  64
#define BK2  128
#define WPAD2 136              // shorts; same padding idiom as R5 (BK+8)
#define JCH2 2048
#define NIT2 (JCH2 / BK2)      // 16

__global__ __launch_bounds__(512, 4) void k_attn(
    const int*   __restrict__ adj,   // [N][N] int32
    const short* __restrict__ WhT,   // [OUT_F][N] bf16
    const float* __restrict__ src,
    const float* __restrict__ dstv,
    float* __restrict__ numer,       // [N][OUT_F] fp32 (= d_out, pre-zeroed)
    float* __restrict__ denom)       // [N] fp32 (pre-zeroed)
{
    __shared__ short wbuf[2][BM2 * WPAD2];  // 2 x 17408 B

    const int t    = threadIdx.x;
    const int lane = t & 63;
    const int wave = t >> 6;
    const int rg   = blockIdx.x >> 2;     // 0..127
    const int jc   = blockIdx.x & 3;      // 0..3
    const int r0   = rg * BM2;
    const int jb   = jc * JCH2;

    // staging mapping: thread -> (row sm, 16 consecutive j at sk0)
    const int sm  = t >> 3;               // 0..63
    const int sk0 = (t & 7) * 16;         // 0..112
    const float srow = src[r0 + sm];
    const int*   abase = adj  + (size_t)(r0 + sm) * N_NODES + jb + sk0;
    const float* dbase = dstv + jb + sk0;
    short* wp0 = &wbuf[0][sm * WPAD2 + sk0];

    // mfma mapping
    const int ln15 = lane & 15;
    const int q    = lane >> 4;
    const int f0   = wave * 16;
    const short* bbase = WhT + (size_t)(f0 + ln15) * N_NODES + jb + q * 8;

    floatx4 acc[4], dac[4];
#pragma unroll
    for (int rt = 0; rt < 4; ++rt) {
        acc[rt] = (floatx4){0.f, 0.f, 0.f, 0.f};
        dac[rt] = (floatx4){0.f, 0.f, 0.f, 0.f};
    }
    short8 ones;
#pragma unroll
    for (int j = 0; j < 8; ++j) ones[j] = (short)0x3F80;  // bf16 1.0

    // prefetch iter 0: 16 j
    intx4 m[4]; fx4 d[4];
#pragma unroll
    for (int v = 0; v < 4; ++v) {
        m[v] = *(const intx4*)(abase + v * 4);
        d[v] = *(const fx4*)(dbase + v * 4);
    }

    for (int it = 0; it < NIT2; ++it) {
        const int p = it & 1;
        // exp weights from resident regs -> LDS
        short8 w0, w1;
#pragma unroll
        for (int v = 0; v < 4; ++v) {
#pragma unroll
            for (int e = 0; e < 4; ++e) {
                float x = srow + d[v][e];
                float l = fmaxf(x, ALPHA_S * x);
                short res = (m[v][e] > 0) ? f2bf(__expf(l)) : (short)0;
                if (v < 2) w0[v * 4 + e] = res;
                else       w1[(v - 2) * 4 + e] = res;
            }
        }
        {
            short* wp = wp0 + p * (BM2 * WPAD2);
            *(short8*)wp       = w0;
            *(short8*)(wp + 8) = w1;
        }
        // issue next iteration's staging loads (hidden behind barrier + MFMA)
        if (it + 1 < NIT2) {
            const int o = (it + 1) * BK2;
#pragma unroll
            for (int v = 0; v < 4; ++v) {
                m[v] = *(const intx4*)(abase + o + v * 4);
                d[v] = *(const fx4*)(dbase + o + v * 4);
            }
        }
        __syncthreads();
        // MFMA on current tile
        const short* ab = &wbuf[p][ln15 * WPAD2 + q * 8];
        const short* bb = bbase + it * BK2;
#pragma unroll
        for (int ks = 0; ks < 4; ++ks) {
            short8 bfr = *(const short8*)(bb + ks * 32);
#pragma unroll
            for (int rt = 0; rt < 4; ++rt) {
                short8 af = *(const short8*)(ab + rt * 16 * WPAD2 + ks * 32);
                acc[rt] = __builtin_amdgcn_mfma_f32_16x16x32_bf16(af, bfr, acc[rt], 0, 0, 0);
                if (wave == 0)
                    dac[rt] = __builtin_amdgcn_mfma_f32_16x16x32_bf16(af, ones, dac[rt], 0, 0, 0);
            }
        }
    }

    // epilogue: atomic partial sums (4-way across j-chunks)
#pragma unroll
    for (int rt = 0; rt < 4; ++rt) {
#pragma unroll
        for (int r = 0; r < 4; ++r) {
            atomicAdd(&numer[(size_t)(r0 + rt * 16 + q * 4 + r) * OUT_F + f0 + ln15],
                      acc[rt][r]);
        }
    }
    if (wave == 0 && ln15 == 0) {
#pragma unroll
        for (int rt = 0; rt < 4; ++rt)
#pragma unroll
            for (int r = 0; r < 4; ++r)
                atomicAdd(&denom[r0 + rt * 16 + q * 4 + r], dac[rt][r]);
    }
}

// ---------------------------------------------------------------------------
// k_final: out = ELU(numer/denom), in place. denom==0 guard -> outputs 0
// (diagnostic: "k_attn contributed nothing" shows as absmax ~0.97, not NaN).
// ---------------------------------------------------------------------------
__global__ void k_final(float* __restrict__ out, const float* __restrict__ denom) {
    const int idx = blockIdx.x * 256 + threadIdx.x;   // grid 4096
    const float dn = denom[idx >> 7];
    float v = (dn != 0.f) ? (out[idx] / dn) : 0.f;
    v = v > 0.f ? v : (__expf(v) - 1.f);
    out[idx] = v;
}

// ---------------------------------------------------------------------------
extern "C" void kernel_launch(void* const* d_in, const int* in_sizes, int n_in,
                              void* d_out, int out_size, void* d_ws, size_t ws_size,
                              hipStream_t stream) {
    const float* h   = (const float*)d_in[0];   // fp32 [8192][256]
    const int*   adj = (const int*)d_in[1];     // int32 [8192][8192]
    const float* W   = (const float*)d_in[2];   // fp32 [256][128]
    const float* a   = (const float*)d_in[3];   // fp32 [256]
    float* out = (float*)d_out;                 // fp32 [8192][128]

    char*  ws    = (char*)d_ws;
    float* denom = (float*)ws;                                  // 32 KB
    short* WhT   = (short*)(ws + 32768);                        // 2 MB
    float* src   = (float*)(ws + 32768 + (size_t)OUT_F * N_NODES * 2);
    float* dst   = src + N_NODES;                               // 32 KB each

    k_zero <<<1032, 256, 0, stream>>>((float4*)out, (float4*)denom);
    k_wh   <<<256, 512, 0, stream>>>(h, W, a, WhT, src, dst);
    k_attn <<<512, 512, 0, stream>>>(adj, WhT, src, dst, out, denom);
    k_final<<<4096, 256, 0, stream>>>(out, denom);
}

// Round 8
// 405.980 us; speedup vs baseline: 1.4758x; 1.4758x over previous
//
#include <hip/hip_runtime.h>

#define N_NODES 8192
#define IN_F    256
#define OUT_F   128
#define ALPHA_S 0.2f

typedef __attribute__((ext_vector_type(8))) short  short8;
typedef __attribute__((ext_vector_type(4))) short  short4v;
typedef __attribute__((ext_vector_type(4))) float  floatx4;
typedef __attribute__((ext_vector_type(4))) int    intx4;
typedef __attribute__((ext_vector_type(4))) float  fx4;

static __device__ __forceinline__ short f2bf(float f) {
    union { float f; unsigned int i; } u; u.f = f;
    unsigned int r = u.i + 0x7FFFu + ((u.i >> 16) & 1u);  // RNE
    return (short)(r >> 16);
}

// ---------------------------------------------------------------------------
// k_wh: Wh = h @ W via bf16 MFMA -> WhT bf16 [OUT_F][N_NODES].
//       src/dst fp32-exact via q1=W@a1, q2=W@a2 folded into W staging.
// 256 blocks x 512 threads, 32 rows/block. (validated R5/R7; unchanged)
// ---------------------------------------------------------------------------
__global__ __launch_bounds__(512) void k_wh(
    const float* __restrict__ h,    // [N][IN_F] fp32
    const float* __restrict__ W,    // [IN_F][OUT_F] fp32
    const float* __restrict__ a,    // [2*OUT_F] fp32
    short* __restrict__ WhT,        // [OUT_F][N] bf16
    float* __restrict__ src,
    float* __restrict__ dst)
{
    __shared__ short Wt[OUT_F][IN_F + 8];
    __shared__ short htile[32][IN_F + 8];
    __shared__ float q1s[IN_F], q2s[IN_F];
    __shared__ short wh_t[OUT_F][40];

    const int t      = threadIdx.x;
    const int lane   = t & 63;
    const int wave   = t >> 6;
    const int r_base = blockIdx.x * 32;

#pragma unroll
    for (int rep = 0; rep < 4; ++rep) {
        const int idx = rep * 8192 + t * 16;
        const int k   = idx >> 7;
        const int f   = idx & 127;
        fx4 w0 = *(const fx4*)(W + idx);
        fx4 w1 = *(const fx4*)(W + idx + 4);
        fx4 w2 = *(const fx4*)(W + idx + 8);
        fx4 w3 = *(const fx4*)(W + idx + 12);
        fx4 a10 = *(const fx4*)(a + f);
        fx4 a11 = *(const fx4*)(a + f + 4);
        fx4 a12 = *(const fx4*)(a + f + 8);
        fx4 a13 = *(const fx4*)(a + f + 12);
        fx4 a20 = *(const fx4*)(a + OUT_F + f);
        fx4 a21 = *(const fx4*)(a + OUT_F + f + 4);
        fx4 a22 = *(const fx4*)(a + OUT_F + f + 8);
        fx4 a23 = *(const fx4*)(a + OUT_F + f + 12);
        float p1 = 0.f, p2 = 0.f;
#pragma unroll
        for (int e = 0; e < 4; ++e) {
            p1 = fmaf(w0[e], a10[e], p1); p2 = fmaf(w0[e], a20[e], p2);
            p1 = fmaf(w1[e], a11[e], p1); p2 = fmaf(w1[e], a21[e], p2);
            p1 = fmaf(w2[e], a12[e], p1); p2 = fmaf(w2[e], a22[e], p2);
            p1 = fmaf(w3[e], a13[e], p1); p2 = fmaf(w3[e], a23[e], p2);
        }
#pragma unroll
        for (int e = 0; e < 4; ++e) {
            Wt[f + e][k]      = f2bf(w0[e]);
            Wt[f + 4 + e][k]  = f2bf(w1[e]);
            Wt[f + 8 + e][k]  = f2bf(w2[e]);
            Wt[f + 12 + e][k] = f2bf(w3[e]);
        }
#pragma unroll
        for (int m = 1; m < 8; m <<= 1) {
            p1 += __shfl_xor(p1, m, 64);
            p2 += __shfl_xor(p2, m, 64);
        }
        if ((t & 7) == 0) { q1s[k] = p1; q2s[k] = p2; }
    }

    const int r0   = t >> 4;
    const int fgrp = t & 15;
    const int k0   = fgrp * 16;
    fx4 h0, h1, h2, h3;
    {
        const float* hp = h + (size_t)(r_base + r0) * IN_F + k0;
        h0 = *(const fx4*)hp; h1 = *(const fx4*)(hp + 4);
        h2 = *(const fx4*)(hp + 8); h3 = *(const fx4*)(hp + 12);
        short8 b0, b1;
#pragma unroll
        for (int e = 0; e < 4; ++e) {
            b0[e]     = f2bf(h0[e]); b0[4 + e] = f2bf(h1[e]);
            b1[e]     = f2bf(h2[e]); b1[4 + e] = f2bf(h3[e]);
        }
        *(short8*)&htile[r0][k0]     = b0;
        *(short8*)&htile[r0][k0 + 8] = b1;
    }
    __syncthreads();

    {
        float sp = 0.f, dp = 0.f;
#pragma unroll
        for (int e = 0; e < 4; ++e) {
            sp = fmaf(h0[e], q1s[k0 + e], sp);      dp = fmaf(h0[e], q2s[k0 + e], dp);
            sp = fmaf(h1[e], q1s[k0 + 4 + e], sp);  dp = fmaf(h1[e], q2s[k0 + 4 + e], dp);
            sp = fmaf(h2[e], q1s[k0 + 8 + e], sp);  dp = fmaf(h2[e], q2s[k0 + 8 + e], dp);
            sp = fmaf(h3[e], q1s[k0 + 12 + e], sp); dp = fmaf(h3[e], q2s[k0 + 12 + e], dp);
        }
#pragma unroll
        for (int m = 1; m < 16; m <<= 1) {
            sp += __shfl_xor(sp, m, 64);
            dp += __shfl_xor(dp, m, 64);
        }
        if (fgrp == 0) { src[r_base + r0] = sp; dst[r_base + r0] = dp; }
    }

    const int ln15 = lane & 15;
    const int q    = lane >> 4;
    const int f0   = wave * 16;
    floatx4 c0 = {0.f, 0.f, 0.f, 0.f};
    floatx4 c1 = {0.f, 0.f, 0.f, 0.f};
#pragma unroll
    for (int s = 0; s < 8; ++s) {
        short8 bf  = *(const short8*)&Wt[f0 + ln15][s * 32 + q * 8];
        short8 a0f = *(const short8*)&htile[ln15][s * 32 + q * 8];
        short8 a1f = *(const short8*)&htile[16 + ln15][s * 32 + q * 8];
        c0 = __builtin_amdgcn_mfma_f32_16x16x32_bf16(a0f, bf, c0, 0, 0, 0);
        c1 = __builtin_amdgcn_mfma_f32_16x16x32_bf16(a1f, bf, c1, 0, 0, 0);
    }
    {
        short4v p0, p1;
#pragma unroll
        for (int r = 0; r < 4; ++r) { p0[r] = f2bf(c0[r]); p1[r] = f2bf(c1[r]); }
        *(short4v*)&wh_t[f0 + ln15][q * 4]      = p0;
        *(short4v*)&wh_t[f0 + ln15][16 + q * 4] = p1;
    }
    __syncthreads();
    {
        const int f    = t >> 2;
        const int half = t & 3;
        *(short8*)(WhT + (size_t)f * N_NODES + r_base + half * 8) =
            *(const short8*)&wh_t[f][half * 8];
    }
}

// ---------------------------------------------------------------------------
// k_attn: EXACT R5-validated structure (BM=32, BK=128, 4-way j-split,
// grid 1024, register-prefetched staging, one barrier/iter), with the
// atomic epilogue replaced by plain coalesced partial stores to ws.
// ---------------------------------------------------------------------------
#define BM 32
#define BK 128
#define WPAD (BK + 8)
#define JCH 2048
#define NIT2 (JCH / BK)   // 16

__global__ __launch_bounds__(512, 4) void k_attn(
    const int*   __restrict__ adj,    // [N][N] int32
    const short* __restrict__ WhT,    // [OUT_F][N] bf16
    const float* __restrict__ src,
    const float* __restrict__ dstv,
    float* __restrict__ numer_part,   // [4][N][OUT_F] fp32
    float* __restrict__ denom_part)   // [4][N] fp32
{
    __shared__ short wbuf[2][BM * WPAD];  // 2 x 8.5 KB

    const int t    = threadIdx.x;
    const int lane = t & 63;
    const int wave = t >> 6;
    const int rg   = blockIdx.x >> 2;
    const int jc   = blockIdx.x & 3;
    const int r0   = rg * BM;
    const int jb   = jc * JCH;

    // staging mapping
    const int sm  = t >> 4;
    const int sk0 = (t & 15) * 8;
    const float srow = src[r0 + sm];
    const int*   abase = adj  + (size_t)(r0 + sm) * N_NODES + jb + sk0;
    const float* dbase = dstv + jb + sk0;

    // mfma mapping
    const int ln15 = lane & 15;
    const int q    = lane >> 4;
    const int f0   = wave * 16;
    const short* bbase = WhT + (size_t)(f0 + ln15) * N_NODES + jb + q * 8;

    floatx4 acc0 = {0.f, 0.f, 0.f, 0.f};
    floatx4 acc1 = {0.f, 0.f, 0.f, 0.f};
    floatx4 dac0 = {0.f, 0.f, 0.f, 0.f};
    floatx4 dac1 = {0.f, 0.f, 0.f, 0.f};
    short8 ones;
#pragma unroll
    for (int j = 0; j < 8; ++j) ones[j] = (short)0x3F80;  // bf16 1.0

    // prefetch iter 0
    intx4 m0 = *(const intx4*)abase;
    intx4 m1 = *(const intx4*)(abase + 4);
    fx4   d0 = *(const fx4*)dbase;
    fx4   d1 = *(const fx4*)(dbase + 4);

    for (int it = 0; it < NIT2; ++it) {
        const int p = it & 1;
        // exp weights from already-resident regs -> LDS
        short8 wv;
#pragma unroll
        for (int e = 0; e < 4; ++e) {
            float x = srow + d0[e];
            float l = fmaxf(x, ALPHA_S * x);
            wv[e] = (m0[e] > 0) ? f2bf(__expf(l)) : (short)0;
        }
#pragma unroll
        for (int e = 0; e < 4; ++e) {
            float x = srow + d1[e];
            float l = fmaxf(x, ALPHA_S * x);
            wv[4 + e] = (m1[e] > 0) ? f2bf(__expf(l)) : (short)0;
        }
        *(short8*)&wbuf[p][sm * WPAD + sk0] = wv;
        // issue next iteration's staging loads (hidden behind barrier + MFMA)
        if (it + 1 < NIT2) {
            const int o = (it + 1) * BK;
            m0 = *(const intx4*)(abase + o);
            m1 = *(const intx4*)(abase + o + 4);
            d0 = *(const fx4*)(dbase + o);
            d1 = *(const fx4*)(dbase + o + 4);
        }
        __syncthreads();
        // MFMA on current tile
        const short* ab = &wbuf[p][ln15 * WPAD + q * 8];
        const short* bb = bbase + it * BK;
#pragma unroll
        for (int ks = 0; ks < 4; ++ks) {
            short8 afr0 = *(const short8*)(ab + ks * 32);
            short8 afr1 = *(const short8*)(ab + 16 * WPAD + ks * 32);
            short8 bfr  = *(const short8*)(bb + ks * 32);
            acc0 = __builtin_amdgcn_mfma_f32_16x16x32_bf16(afr0, bfr, acc0, 0, 0, 0);
            acc1 = __builtin_amdgcn_mfma_f32_16x16x32_bf16(afr1, bfr, acc1, 0, 0, 0);
            if (wave == 0) {
                dac0 = __builtin_amdgcn_mfma_f32_16x16x32_bf16(afr0, ones, dac0, 0, 0, 0);
                dac1 = __builtin_amdgcn_mfma_f32_16x16x32_bf16(afr1, ones, dac1, 0, 0, 0);
            }
        }
    }

    // epilogue: plain partial stores (no atomics)
    float* np = numer_part + ((size_t)jc * N_NODES + r0) * OUT_F;
#pragma unroll
    for (int r = 0; r < 4; ++r) {
        np[(size_t)(q * 4 + r) * OUT_F + f0 + ln15]      = acc0[r];
        np[(size_t)(16 + q * 4 + r) * OUT_F + f0 + ln15] = acc1[r];
    }
    if (wave == 0 && ln15 == 0) {
        float* dp = denom_part + (size_t)jc * N_NODES + r0;
#pragma unroll
        for (int r = 0; r < 4; ++r) {
            dp[q * 4 + r]      = dac0[r];
            dp[16 + q * 4 + r] = dac1[r];
        }
    }
}

// ---------------------------------------------------------------------------
// k_final: out = ELU( (sum_jc numer_part) / (sum_jc denom_part) ).
// denom==0 guard kept as a diagnostic (inert-kernel shows absmax~0.97).
// ---------------------------------------------------------------------------
__global__ void k_final(const float* __restrict__ numer_part,
                        const float* __restrict__ denom_part,
                        float* __restrict__ out) {
    const int idx = blockIdx.x * 256 + threadIdx.x;   // grid 4096
    const int row = idx >> 7;
    float v  = 0.f, dn = 0.f;
#pragma unroll
    for (int jc = 0; jc < 4; ++jc) {
        v  += numer_part[(size_t)jc * N_NODES * OUT_F + idx];
        dn += denom_part[(size_t)jc * N_NODES + row];
    }
    v = (dn != 0.f) ? (v / dn) : 0.f;
    v = v > 0.f ? v : (__expf(v) - 1.f);
    out[idx] = v;
}

// ---------------------------------------------------------------------------
extern "C" void kernel_launch(void* const* d_in, const int* in_sizes, int n_in,
                              void* d_out, int out_size, void* d_ws, size_t ws_size,
                              hipStream_t stream) {
    const float* h   = (const float*)d_in[0];   // fp32 [8192][256]
    const int*   adj = (const int*)d_in[1];     // int32 [8192][8192]
    const float* W   = (const float*)d_in[2];   // fp32 [256][128]
    const float* a   = (const float*)d_in[3];   // fp32 [256]
    float* out = (float*)d_out;                 // fp32 [8192][128]

    char*  ws    = (char*)d_ws;
    float* denom_part = (float*)ws;                             // 4*8192*4 = 128 KB
    short* WhT        = (short*)(ws + (128 << 10));             // 2 MB
    float* src        = (float*)(ws + (128 << 10) + (2 << 20)); // 32 KB
    float* dst        = src + N_NODES;                          // 32 KB
    float* numer_part = (float*)(ws + (4 << 20));               // 16 MB

    k_wh   <<<256, 512, 0, stream>>>(h, W, a, WhT, src, dst);
    k_attn <<<1024, 512, 0, stream>>>(adj, WhT, src, dst, numer_part, denom_part);
    k_final<<<4096, 256, 0, stream>>>(numer_part, denom_part, out);
}